// Round 1
// baseline (283.815 us; speedup 1.0000x reference)
//
#include <hip/hip_runtime.h>
#include <math.h>

#define H 128

typedef _Float16 half8 __attribute__((ext_vector_type(8)));
typedef float f32x16 __attribute__((ext_vector_type(16)));
typedef int int4v __attribute__((ext_vector_type(4)));

__device__ __forceinline__ half8 h8max(half8 a, half8 b) {
#if defined(__has_builtin) && __has_builtin(__builtin_elementwise_max)
    return __builtin_elementwise_max(a, b);
#else
    half8 r;
#pragma unroll
    for (int j = 0; j < 8; ++j) r[j] = a[j] > b[j] ? a[j] : b[j];
    return r;
#endif
}

__device__ __forceinline__ half8 h8shfl_xor(half8 v, int mask) {
    int4v iv;
    __builtin_memcpy(&iv, &v, 16);
#pragma unroll
    for (int j = 0; j < 4; ++j) iv[j] = __shfl_xor(iv[j], mask, 64);
    half8 r;
    __builtin_memcpy(&r, &iv, 16);
    return r;
}

// ---------------- CSR build ----------------

__global__ __launch_bounds__(256) void scan_atomic(const int* __restrict__ deg,
                                                   int* __restrict__ offsets,
                                                   int* __restrict__ gcur, int N) {
    __shared__ int buf[256];
    __shared__ int sbase;
    int tid = threadIdx.x;
    int i = blockIdx.x * 256 + tid;
    int v = (i < N) ? deg[i] : 0;
    int incl = v;
    buf[tid] = v;
    __syncthreads();
#pragma unroll
    for (int off = 1; off < 256; off <<= 1) {
        int t = (tid >= off) ? buf[tid - off] : 0;
        __syncthreads();
        incl += t;
        buf[tid] = incl;
        __syncthreads();
    }
    if (tid == 255) sbase = atomicAdd(gcur, incl);
    __syncthreads();
    if (i < N) offsets[i] = sbase + incl - v;
}

__global__ __launch_bounds__(256) void fill_adj(const int* __restrict__ ei, int E,
                                                const int* __restrict__ offsets,
                                                int* __restrict__ cursor,
                                                int* __restrict__ adj) {
    int e = blockIdx.x * 256 + threadIdx.x;
    if (e < E) {
        int s = ei[e];
        int d = ei[E + e];
        int pos = atomicAdd(&cursor[d], 1);
        adj[offsets[d] + pos] = s;
    }
}

// ---------------- merged prep ----------------

__global__ __launch_bounds__(256) void prep_all(
    const int* __restrict__ ei, int E, int* __restrict__ deg,
    const float* __restrict__ x, const float* __restrict__ query,
    const float* __restrict__ Wl, const float* __restrict__ Wr,
    const float* __restrict__ Wlin, _Float16* __restrict__ xh,
    _Float16* __restrict__ wimg, float* __restrict__ qn, int n8, int HB, int SB,
    int WB) {
    int b = blockIdx.x;
    int tid = threadIdx.x;
    if (b < HB) {
        int e = b * 256 + tid;
        if (e < E) atomicAdd(&deg[ei[E + e]], 1);
    } else if (b < HB + SB) {
        int i = (b - HB) * 256 + tid;
        if (i < n8) {
            const float4* x4 = (const float4*)x;
            float4 u = x4[(size_t)i * 2], v = x4[(size_t)i * 2 + 1];
            float f[8] = {u.x, u.y, u.z, u.w, v.x, v.y, v.z, v.w};
            half8 h;
#pragma unroll
            for (int j = 0; j < 8; ++j) h[j] = (_Float16)f[j];
            *(half8*)(xh + (size_t)i * 8) = h;
        }
    } else if (b < HB + SB + WB) {
        int gidx = (b - HB - SB) * 256 + tid;
        if (gidx < 7 * 2048) {
            int mat = gidx / 2048;
            int rem = gidx - mat * 2048;
            int n = rem >> 4;
            int g = rem & 15;
            const float* src = (mat == 6) ? Wlin
                             : ((mat & 1) ? Wr + (mat >> 1) * H * H
                                          : Wl + (mat >> 1) * H * H);
            const float* p = src + n * H + g * 8;
            half8 h, l;
#pragma unroll
            for (int j = 0; j < 8; ++j) {
                float v = p[j];
                _Float16 hh = (_Float16)v;
                h[j] = hh;
                l[j] = (_Float16)(v - (float)hh);
            }
            int kc4 = g >> 2, gpc = g & 3;
            int posB = (gpc + (n & 3) + ((n >> 2) & 3)) & 3;
            size_t base = (size_t)mat * 32768 + (size_t)kc4 * 8192 + n * 32 + posB * 8;
            *(half8*)(wimg + base) = h;
            *(half8*)(wimg + base + 4096) = l;
        }
    } else {
        int g = b - HB - SB - WB;
        __shared__ float part[4];
        float v = (tid < 128) ? query[g * H + tid] : 0.f;
        float ss = v * v;
#pragma unroll
        for (int off = 32; off > 0; off >>= 1) ss += __shfl_xor(ss, off, 64);
        if ((tid & 63) == 0) part[tid >> 6] = ss;
        __syncthreads();
        float tot = part[0] + part[1];
        if (tid < 128) qn[g * H + tid] = v / fmaxf(sqrtf(tot), 1e-12f);
    }
}

// ---------------- fused layer (+ optional final linear/cosine) -----------
// Y = relu(segmax(X) @ Wl^T + bias + X @ Wr^T).
// Gather v2: adjacency preloaded into 8 regs/lane (entry (node-pair,slot)
// lives at lane (node&1)*32+slot of reg node>>1), consumed via shfl; node
// loop FULLY unrolled, branch-free 32-slot body (valid when wave dmax<=32;
// rare waves take the original general path). Removes the adj->Xh dependent
// hop and lets loads of many nodes pipeline.
// FINAL: keep relu'd Y in LDS (pass-0 XOR-16 image), run Wlin GEMM pass,
// cosine epilogue with cross-wave combine through sB. No Y round-trip.

template <bool FINAL>
__global__ __launch_bounds__(256) void layer_fused(
    const half8* __restrict__ Xh, const int* __restrict__ deg,
    const int* __restrict__ offsets, const int* __restrict__ adj,
    const _Float16* __restrict__ Bimg, const float* __restrict__ bias,
    _Float16* __restrict__ Yh, const _Float16* __restrict__ BimgF,
    const float* __restrict__ blin, const float* __restrict__ qn,
    const int* __restrict__ bv, float* __restrict__ out, int N) {
    __shared__ __align__(16) _Float16 sU[8192];  // m/Y image (full K) or x chunk
    __shared__ __align__(16) _Float16 sB[8192];  // B chunk hi(4096)+lo(4096)

    int tid = threadIdx.x;
    int w = tid >> 6;
    int lane = tid & 63;
    int l31 = lane & 31;
    int lhi = lane >> 5;
    int ws = w >> 1;
    int wc = w & 1;
    int n0 = blockIdx.x * 64;

    // ---- Phase G: gather segment-max ----
    {
        int sub = lane >> 4;
        int lf = lane & 15;
        const _Float16 ni = (_Float16)(-INFINITY);
        const half8 ninf = {ni, ni, ni, ni, ni, ni, ni, ni};
        const half8 hz = {(_Float16)0.f, (_Float16)0.f, (_Float16)0.f, (_Float16)0.f,
                          (_Float16)0.f, (_Float16)0.f, (_Float16)0.f, (_Float16)0.f};
        int nd = n0 + w * 16 + lf;
        int ndc = nd < N ? nd : N - 1;
        int e0v = offsets[ndc];
        int degv = (nd < N) ? deg[ndc] : 0;

        int dmx = degv;
#pragma unroll
        for (int off = 1; off <= 8; off <<= 1) {
            int t = __shfl_xor(dmx, off, 64);
            dmx = t > dmx ? t : dmx;
        }

        if (dmx <= 32) {
            // adjacency preload: reg rr holds nodes (2rr, 2rr+1); lane l
            // holds slot l&31 of node 2rr + (l>>5), clamped to last entry.
            int adjf[8];
#pragma unroll
            for (int rr = 0; rr < 8; ++rr) {
                int i = 2 * rr + (lane >> 5);
                int e0 = __shfl(e0v, i, 64);
                int d = __shfl(degv, i, 64);
                int s = lane & 31;
                int p = d > 0 ? e0 + (s < d ? s : d - 1) : 0;
                adjf[rr] = adj[p];
            }
#pragma unroll
            for (int i = 0; i < 16; ++i) {
                int d = __shfl(degv, i, 64);
                int dm1 = d > 0 ? d - 1 : 0;
                half8 v[8];
#pragma unroll
                for (int q = 0; q < 8; ++q) {
                    int j = q * 4 + sub;
                    int jc = j < d ? j : dm1;
                    int idx = __shfl(adjf[i >> 1], ((i & 1) << 5) | jc, 64);
                    v[q] = Xh[(size_t)idx * 16 + lf];
                }
                half8 acc = h8max(h8max(h8max(v[0], v[1]), h8max(v[2], v[3])),
                                  h8max(h8max(v[4], v[5]), h8max(v[6], v[7])));
                acc = h8max(acc, h8shfl_xor(acc, 16));
                acc = h8max(acc, h8shfl_xor(acc, 32));
                if (d == 0) acc = hz;
                int row = w * 16 + i;
                if (sub == 0) *(half8*)&sU[row * 128 + ((lf ^ (row & 15)) << 3)] = acc;
            }
        } else {
            // general path (rare): original wave-per-node loop
            for (int i = 0; i < 16; ++i) {
                int e0 = __shfl(e0v, i, 64);
                int d = __shfl(degv, i, 64);
                int row = w * 16 + i;
                half8 acc = ninf;
                for (int base = 0; base < d; base += 16) {
                    half8 v[4];
#pragma unroll
                    for (int q = 0; q < 4; ++q) {
                        int j = base + q * 4 + sub;
                        int idx = adj[e0 + (j < d ? j : d - 1)];
                        v[q] = Xh[(size_t)idx * 16 + lf];
                    }
                    acc = h8max(acc, h8max(h8max(v[0], v[1]), h8max(v[2], v[3])));
                }
                acc = h8max(acc, h8shfl_xor(acc, 16));
                acc = h8max(acc, h8shfl_xor(acc, 32));
                if (d == 0) acc = hz;
                if (sub == 0) *(half8*)&sU[row * 128 + ((lf ^ (row & 15)) << 3)] = acc;
            }
        }
    }
    __syncthreads();

    f32x16 acc[2];
#pragma unroll
    for (int nt = 0; nt < 2; ++nt) {
        float bvv = bias[wc * 64 + nt * 32 + l31];
#pragma unroll
        for (int r = 0; r < 16; ++r) acc[nt][r] = bvv;
    }

    int rl = ws * 32 + l31;

    // ---- Pass 0: m @ Wl^T ----
    for (int kc4 = 0; kc4 < 4; ++kc4) {
        if (kc4) __syncthreads();
        {
            const half8* bsrc = (const half8*)(Bimg + (size_t)kc4 * 8192);
            half8* bdst = (half8*)sB;
#pragma unroll
            for (int i = 0; i < 4; ++i) bdst[tid + i * 256] = bsrc[tid + i * 256];
        }
        __syncthreads();
#pragma unroll
        for (int ks = 0; ks < 2; ++ks) {
            int g16 = kc4 * 4 + ks * 2 + lhi;
            int posA = g16 ^ (rl & 15);
            half8 ah = *(const half8*)&sU[rl * 128 + posA * 8];
#pragma unroll
            for (int nt = 0; nt < 2; ++nt) {
                int n = wc * 64 + nt * 32 + l31;
                int gpc = ks * 2 + lhi;
                int posB = (gpc + (n & 3) + ((n >> 2) & 3)) & 3;
                half8 bh = *(const half8*)&sB[n * 32 + posB * 8];
                half8 bl2 = *(const half8*)&sB[4096 + n * 32 + posB * 8];
                acc[nt] = __builtin_amdgcn_mfma_f32_32x32x16_f16(ah, bh, acc[nt], 0, 0, 0);
                acc[nt] = __builtin_amdgcn_mfma_f32_32x32x16_f16(ah, bl2, acc[nt], 0, 0, 0);
            }
        }
    }

    // ---- Pass 1: x @ Wr^T ----
    for (int kc4 = 0; kc4 < 4; ++kc4) {
        __syncthreads();
        {
            const half8* bsrc = (const half8*)(Bimg + 32768 + (size_t)kc4 * 8192);
            half8* bdst = (half8*)sB;
#pragma unroll
            for (int i = 0; i < 4; ++i) bdst[tid + i * 256] = bsrc[tid + i * 256];
        }
        if ((kc4 & 1) == 0) {
            int kc64 = kc4 >> 1;
#pragma unroll
            for (int i = 0; i < 2; ++i) {
                int idx = tid + i * 256;
                int row = idx >> 3;
                int gp8 = idx & 7;
                int n = n0 + row;
                half8 h = {(_Float16)0.f, (_Float16)0.f, (_Float16)0.f, (_Float16)0.f,
                           (_Float16)0.f, (_Float16)0.f, (_Float16)0.f, (_Float16)0.f};
                if (n < N) h = Xh[(size_t)n * 16 + kc64 * 8 + gp8];
                int pos8 = (gp8 + (row & 7) + ((row >> 3) & 7)) & 7;
                *(half8*)&sU[row * 72 + pos8 * 8] = h;
            }
        }
        __syncthreads();
#pragma unroll
        for (int ks = 0; ks < 2; ++ks) {
            int gp8 = (kc4 & 1) * 4 + ks * 2 + lhi;
            int posA8 = (gp8 + (rl & 7) + ((rl >> 3) & 7)) & 7;
            half8 ah = *(const half8*)&sU[rl * 72 + posA8 * 8];
#pragma unroll
            for (int nt = 0; nt < 2; ++nt) {
                int n = wc * 64 + nt * 32 + l31;
                int gpc = ks * 2 + lhi;
                int posB = (gpc + (n & 3) + ((n >> 2) & 3)) & 3;
                half8 bh = *(const half8*)&sB[n * 32 + posB * 8];
                half8 bl2 = *(const half8*)&sB[4096 + n * 32 + posB * 8];
                acc[nt] = __builtin_amdgcn_mfma_f32_32x32x16_f16(ah, bh, acc[nt], 0, 0, 0);
                acc[nt] = __builtin_amdgcn_mfma_f32_32x32x16_f16(ah, bl2, acc[nt], 0, 0, 0);
            }
        }
    }

    if constexpr (!FINAL) {
        // epilogue: relu + fp16 store. row=(r&3)+8*(r>>2)+4*lhi, col=l31 base
#pragma unroll
        for (int r = 0; r < 16; ++r) {
            int row = n0 + ws * 32 + (r & 3) + 8 * (r >> 2) + 4 * lhi;
            if (row < N) {
#pragma unroll
                for (int nt = 0; nt < 2; ++nt) {
                    int col = wc * 64 + nt * 32 + l31;
                    Yh[(size_t)row * H + col] = (_Float16)fmaxf(acc[nt][r], 0.f);
                }
            }
        }
    } else {
        // ---- FINAL: Y -> sU full-K image (pass-0 XOR-16 layout) ----
        __syncthreads();  // all pass-1 sU/sB reads done
#pragma unroll
        for (int r = 0; r < 16; ++r) {
            int rloc = ws * 32 + (r & 3) + 8 * (r >> 2) + 4 * lhi;
#pragma unroll
            for (int nt = 0; nt < 2; ++nt) {
                int c = wc * 64 + nt * 32 + l31;
                sU[rloc * 128 + (((c >> 3) ^ (rloc & 15)) << 3) + (c & 7)] =
                    (_Float16)fmaxf(acc[nt][r], 0.f);
            }
        }

        f32x16 acc2[2];
#pragma unroll
        for (int nt = 0; nt < 2; ++nt) {
            float b = blin[wc * 64 + nt * 32 + l31];
#pragma unroll
            for (int r = 0; r < 16; ++r) acc2[nt][r] = b;
        }

        // ---- Pass F: Y @ Wlin^T ----
        for (int kc4 = 0; kc4 < 4; ++kc4) {
            __syncthreads();  // first iter also covers Y-image visibility
            {
                const half8* bsrc = (const half8*)(BimgF + (size_t)kc4 * 8192);
                half8* bdst = (half8*)sB;
#pragma unroll
                for (int i = 0; i < 4; ++i) bdst[tid + i * 256] = bsrc[tid + i * 256];
            }
            __syncthreads();
#pragma unroll
            for (int ks = 0; ks < 2; ++ks) {
                int g16 = kc4 * 4 + ks * 2 + lhi;
                int posA = g16 ^ (rl & 15);
                half8 ah = *(const half8*)&sU[rl * 128 + posA * 8];
#pragma unroll
                for (int nt = 0; nt < 2; ++nt) {
                    int n = wc * 64 + nt * 32 + l31;
                    int gpc = ks * 2 + lhi;
                    int posB = (gpc + (n & 3) + ((n >> 2) & 3)) & 3;
                    half8 bh = *(const half8*)&sB[n * 32 + posB * 8];
                    half8 bl2 = *(const half8*)&sB[4096 + n * 32 + posB * 8];
                    acc2[nt] = __builtin_amdgcn_mfma_f32_32x32x16_f16(ah, bh, acc2[nt], 0, 0, 0);
                    acc2[nt] = __builtin_amdgcn_mfma_f32_32x32x16_f16(ah, bl2, acc2[nt], 0, 0, 0);
                }
            }
        }

        // ---- cosine epilogue: per-row partials, cross-wc combine via sB ----
        int rgl = n0 + ws * 32 + l31;
        rgl = rgl < N ? rgl : N - 1;
        int gl = bv[rgl];
        __syncthreads();  // done reading sB chunk; reuse as float scratch
        float* sP = (float*)sB;  // [64 rows][wc][ss,sd] = 1 KB
#pragma unroll
        for (int r = 0; r < 16; ++r) {
            int rloc = (r & 3) + 8 * (r >> 2) + 4 * lhi;
            int g = __shfl(gl, rloc, 32);
            float ss = 0.f, sd = 0.f;
#pragma unroll
            for (int nt = 0; nt < 2; ++nt) {
                float y = acc2[nt][r];
                float q = qn[(size_t)g * H + wc * 64 + nt * 32 + l31];
                ss = fmaf(y, y, ss);
                sd = fmaf(y, q, sd);
            }
#pragma unroll
            for (int off = 1; off <= 16; off <<= 1) {
                ss += __shfl_xor(ss, off, 64);
                sd += __shfl_xor(sd, off, 64);
            }
            if (l31 == 0) {
                int rowl = ws * 32 + rloc;
                sP[rowl * 4 + wc * 2] = ss;
                sP[rowl * 4 + wc * 2 + 1] = sd;
            }
        }
        __syncthreads();
        if (tid < 64) {
            int row = n0 + tid;
            if (row < N) {
                float ss = sP[tid * 4] + sP[tid * 4 + 2];
                float sd = sP[tid * 4 + 1] + sP[tid * 4 + 3];
                out[row] = sd / fmaxf(sqrtf(ss), 1e-12f);
            }
        }
    }
}

// ---------------- launch ----------------

extern "C" void kernel_launch(void* const* d_in, const int* in_sizes, int n_in,
                              void* d_out, int out_size, void* d_ws, size_t ws_size,
                              hipStream_t stream) {
    const float* x = (const float*)d_in[0];
    const float* query = (const float*)d_in[1];
    const float* Wl = (const float*)d_in[2];
    const float* bl = (const float*)d_in[3];
    const float* Wr = (const float*)d_in[4];
    const float* Wlin = (const float*)d_in[5];
    const float* blin = (const float*)d_in[6];
    const int* ei = (const int*)d_in[7];
    const int* bv = (const int*)d_in[8];
    float* out = (float*)d_out;

    const int N = in_sizes[0] / H;
    const int E = in_sizes[7] / 2;
    const int G = in_sizes[1] / H;

    char* p = (char*)d_ws;
    auto alloc = [&](size_t bytes) {
        char* r = p;
        p += (bytes + 255) & ~(size_t)255;
        return r;
    };
    int* deg = (int*)alloc((size_t)(2 * N + 1) * sizeof(int));  // deg|cursor|gcur
    int* cursor = deg + N;
    int* gcur = deg + 2 * N;
    int* offsets = (int*)alloc((size_t)N * sizeof(int));
    int* adj = (int*)alloc((size_t)E * sizeof(int));
    float* qn = (float*)alloc((size_t)G * H * sizeof(float));
    _Float16* wimg = (_Float16*)alloc((size_t)7 * 32768 * sizeof(_Float16));
    size_t actH = (size_t)N * H * sizeof(_Float16);
    _Float16* xah = (_Float16*)alloc(actH);
    _Float16* xbh = (_Float16*)alloc(actH);

    hipMemsetAsync(deg, 0, (size_t)(2 * N + 1) * sizeof(int), stream);

    const int n8 = N * H / 8;
    const int HB = (E + 255) / 256;
    const int SB = (n8 + 255) / 256;
    const int WB = (7 * 2048 + 255) / 256;
    prep_all<<<HB + SB + WB + G, 256, 0, stream>>>(ei, E, deg, x, query, Wl, Wr,
                                                   Wlin, xah, wimg, qn, n8, HB,
                                                   SB, WB);
    scan_atomic<<<(N + 255) / 256, 256, 0, stream>>>(deg, offsets, gcur, N);
    fill_adj<<<(E + 255) / 256, 256, 0, stream>>>(ei, E, offsets, cursor, adj);

    const int NGm = (N + 63) / 64;

    layer_fused<false><<<NGm, 256, 0, stream>>>(
        (const half8*)xah, deg, offsets, adj, wimg + (size_t)0 * 65536,
        bl + 0 * H, xbh, nullptr, nullptr, nullptr, nullptr, nullptr, N);
    layer_fused<false><<<NGm, 256, 0, stream>>>(
        (const half8*)xbh, deg, offsets, adj, wimg + (size_t)1 * 65536,
        bl + 1 * H, xah, nullptr, nullptr, nullptr, nullptr, nullptr, N);
    layer_fused<true><<<NGm, 256, 0, stream>>>(
        (const half8*)xah, deg, offsets, adj, wimg + (size_t)2 * 65536,
        bl + 2 * H, nullptr, wimg + (size_t)6 * 32768, blin, qn, bv, out, N);
}

// Round 2
// 272.718 us; speedup vs baseline: 1.0407x; 1.0407x over previous
//
#include <hip/hip_runtime.h>
#include <math.h>

#define H 128

typedef _Float16 half8 __attribute__((ext_vector_type(8)));
typedef float f32x16 __attribute__((ext_vector_type(16)));
typedef int int4v __attribute__((ext_vector_type(4)));

__device__ __forceinline__ half8 h8max(half8 a, half8 b) {
#if defined(__has_builtin) && __has_builtin(__builtin_elementwise_max)
    return __builtin_elementwise_max(a, b);
#else
    half8 r;
#pragma unroll
    for (int j = 0; j < 8; ++j) r[j] = a[j] > b[j] ? a[j] : b[j];
    return r;
#endif
}

__device__ __forceinline__ half8 h8shfl_xor(half8 v, int mask) {
    int4v iv;
    __builtin_memcpy(&iv, &v, 16);
#pragma unroll
    for (int j = 0; j < 4; ++j) iv[j] = __shfl_xor(iv[j], mask, 64);
    half8 r;
    __builtin_memcpy(&r, &iv, 16);
    return r;
}

// ---------------- CSR build ----------------

__global__ __launch_bounds__(256) void scan_atomic(const int* __restrict__ deg,
                                                   int* __restrict__ offsets,
                                                   int* __restrict__ gcur, int N) {
    __shared__ int buf[256];
    __shared__ int sbase;
    int tid = threadIdx.x;
    int i = blockIdx.x * 256 + tid;
    int v = (i < N) ? deg[i] : 0;
    int incl = v;
    buf[tid] = v;
    __syncthreads();
#pragma unroll
    for (int off = 1; off < 256; off <<= 1) {
        int t = (tid >= off) ? buf[tid - off] : 0;
        __syncthreads();
        incl += t;
        buf[tid] = incl;
        __syncthreads();
    }
    if (tid == 255) sbase = atomicAdd(gcur, incl);
    __syncthreads();
    if (i < N) offsets[i] = sbase + incl - v;
}

__global__ __launch_bounds__(256) void fill_adj(const int* __restrict__ ei, int E,
                                                const int* __restrict__ offsets,
                                                int* __restrict__ cursor,
                                                int* __restrict__ adj) {
    int e = blockIdx.x * 256 + threadIdx.x;
    if (e < E) {
        int s = ei[e];
        int d = ei[E + e];
        int pos = atomicAdd(&cursor[d], 1);
        adj[offsets[d] + pos] = s;
    }
}

// ---------------- merged prep ----------------

__global__ __launch_bounds__(256) void prep_all(
    const int* __restrict__ ei, int E, int* __restrict__ deg,
    const float* __restrict__ x, const float* __restrict__ query,
    const float* __restrict__ Wl, const float* __restrict__ Wr,
    const float* __restrict__ Wlin, _Float16* __restrict__ xh,
    _Float16* __restrict__ wimg, float* __restrict__ qn, int n8, int HB, int SB,
    int WB) {
    int b = blockIdx.x;
    int tid = threadIdx.x;
    if (b < HB) {
        int e = b * 256 + tid;
        if (e < E) atomicAdd(&deg[ei[E + e]], 1);
    } else if (b < HB + SB) {
        int i = (b - HB) * 256 + tid;
        if (i < n8) {
            const float4* x4 = (const float4*)x;
            float4 u = x4[(size_t)i * 2], v = x4[(size_t)i * 2 + 1];
            float f[8] = {u.x, u.y, u.z, u.w, v.x, v.y, v.z, v.w};
            half8 h;
#pragma unroll
            for (int j = 0; j < 8; ++j) h[j] = (_Float16)f[j];
            *(half8*)(xh + (size_t)i * 8) = h;
        }
    } else if (b < HB + SB + WB) {
        int gidx = (b - HB - SB) * 256 + tid;
        if (gidx < 7 * 2048) {
            int mat = gidx / 2048;
            int rem = gidx - mat * 2048;
            int n = rem >> 4;
            int g = rem & 15;
            const float* src = (mat == 6) ? Wlin
                             : ((mat & 1) ? Wr + (mat >> 1) * H * H
                                          : Wl + (mat >> 1) * H * H);
            const float* p = src + n * H + g * 8;
            half8 h, l;
#pragma unroll
            for (int j = 0; j < 8; ++j) {
                float v = p[j];
                _Float16 hh = (_Float16)v;
                h[j] = hh;
                l[j] = (_Float16)(v - (float)hh);
            }
            int kc4 = g >> 2, gpc = g & 3;
            int posB = (gpc + (n & 3) + ((n >> 2) & 3)) & 3;
            size_t base = (size_t)mat * 32768 + (size_t)kc4 * 8192 + n * 32 + posB * 8;
            *(half8*)(wimg + base) = h;
            *(half8*)(wimg + base + 4096) = l;
        }
    } else {
        int g = b - HB - SB - WB;
        __shared__ float part[4];
        float v = (tid < 128) ? query[g * H + tid] : 0.f;
        float ss = v * v;
#pragma unroll
        for (int off = 32; off > 0; off >>= 1) ss += __shfl_xor(ss, off, 64);
        if ((tid & 63) == 0) part[tid >> 6] = ss;
        __syncthreads();
        float tot = part[0] + part[1];
        if (tid < 128) qn[g * H + tid] = v / fmaxf(sqrtf(tot), 1e-12f);
    }
}

// ---------------- fused layer v3: 32-row tile, direct-global B -------------
// Y = relu(segmax(X) @ Wl^T + bias + X @ Wr^T).
// Tile 32 rows x 128 cols, 4 waves each owning a 32-col quarter (M=32 MFMA).
// B fragments read DIRECTLY from the L2-resident weight image (no sB, no
// staging barriers): pass 0 has ZERO internal syncs; pass 1 has 2 stage
// pairs for the x-chunk. LDS = 8 KB (sU only) -> occupancy capped by the
// 32-wave/CU HW limit, grid 1563 blocks ~ 6 blocks/CU.
// Gather: wave-per-8-nodes, adjacency preloaded to 4 regs/lane, consumed
// via shfl; branch-free 32-slot body when wave dmax<=32 (else general path).

__global__ __launch_bounds__(256, 8) void layer_fused(
    const half8* __restrict__ Xh, const int* __restrict__ deg,
    const int* __restrict__ offsets, const int* __restrict__ adj,
    const _Float16* __restrict__ Bimg, const float* __restrict__ bias,
    _Float16* __restrict__ Yh, int N) {
    __shared__ __align__(16) _Float16 sU[4096];  // m image (32x128) / x chunk

    int tid = threadIdx.x;
    int w = tid >> 6;
    int lane = tid & 63;
    int l31 = lane & 31;
    int lhi = lane >> 5;
    int n0 = blockIdx.x * 32;

    // ---- Phase G: gather segment-max (8 nodes per wave) ----
    {
        int sub = lane >> 4;
        int lf = lane & 15;
        const _Float16 ni = (_Float16)(-INFINITY);
        const half8 ninf = {ni, ni, ni, ni, ni, ni, ni, ni};
        const half8 hz = {(_Float16)0.f, (_Float16)0.f, (_Float16)0.f, (_Float16)0.f,
                          (_Float16)0.f, (_Float16)0.f, (_Float16)0.f, (_Float16)0.f};
        int nd = n0 + w * 8 + (lf & 7);
        int ndc = nd < N ? nd : N - 1;
        int e0v = offsets[ndc];
        int degv = (nd < N) ? deg[ndc] : 0;

        int dmx = degv;
#pragma unroll
        for (int off = 1; off <= 8; off <<= 1) {
            int t = __shfl_xor(dmx, off, 64);
            dmx = t > dmx ? t : dmx;
        }

        if (dmx <= 32) {
            // adjacency preload: reg rr holds nodes (2rr, 2rr+1); lane l
            // holds slot l&31 of node 2rr + (l>>5), clamped to last entry.
            int adjf[4];
#pragma unroll
            for (int rr = 0; rr < 4; ++rr) {
                int i = 2 * rr + (lane >> 5);
                int e0 = __shfl(e0v, i, 64);
                int d = __shfl(degv, i, 64);
                int s = lane & 31;
                int p = d > 0 ? e0 + (s < d ? s : d - 1) : 0;
                adjf[rr] = adj[p];
            }
#pragma unroll
            for (int i = 0; i < 8; ++i) {
                int d = __shfl(degv, i, 64);
                int dm1 = d > 0 ? d - 1 : 0;
                half8 v[8];
#pragma unroll
                for (int q = 0; q < 8; ++q) {
                    int j = q * 4 + sub;
                    int jc = j < d ? j : dm1;
                    int idx = __shfl(adjf[i >> 1], ((i & 1) << 5) | jc, 64);
                    v[q] = Xh[(size_t)idx * 16 + lf];
                }
                half8 acc = h8max(h8max(h8max(v[0], v[1]), h8max(v[2], v[3])),
                                  h8max(h8max(v[4], v[5]), h8max(v[6], v[7])));
                acc = h8max(acc, h8shfl_xor(acc, 16));
                acc = h8max(acc, h8shfl_xor(acc, 32));
                if (d == 0) acc = hz;
                int row = w * 8 + i;
                if (sub == 0) *(half8*)&sU[row * 128 + ((lf ^ (row & 15)) << 3)] = acc;
            }
        } else {
            // general path (rare): wave-per-node loop
            for (int i = 0; i < 8; ++i) {
                int e0 = __shfl(e0v, i, 64);
                int d = __shfl(degv, i, 64);
                int row = w * 8 + i;
                half8 acc = ninf;
                for (int base = 0; base < d; base += 16) {
                    half8 v[4];
#pragma unroll
                    for (int q = 0; q < 4; ++q) {
                        int j = base + q * 4 + sub;
                        int idx = adj[e0 + (j < d ? j : d - 1)];
                        v[q] = Xh[(size_t)idx * 16 + lf];
                    }
                    acc = h8max(acc, h8max(h8max(v[0], v[1]), h8max(v[2], v[3])));
                }
                acc = h8max(acc, h8shfl_xor(acc, 16));
                acc = h8max(acc, h8shfl_xor(acc, 32));
                if (d == 0) acc = hz;
                if (sub == 0) *(half8*)&sU[row * 128 + ((lf ^ (row & 15)) << 3)] = acc;
            }
        }
    }
    __syncthreads();

    f32x16 acc;
    {
        float bvv = bias[w * 32 + l31];
#pragma unroll
        for (int r = 0; r < 16; ++r) acc[r] = bvv;
    }

    int rl = l31;            // A row within the 32-row tile
    int n = w * 32 + l31;    // output column

    // ---- Pass 0: m @ Wl^T (B direct from global; no internal barriers) ----
#pragma unroll
    for (int kc4 = 0; kc4 < 4; ++kc4) {
        const _Float16* Bc = Bimg + (size_t)kc4 * 8192;
#pragma unroll
        for (int ks = 0; ks < 2; ++ks) {
            int g16 = kc4 * 4 + ks * 2 + lhi;
            int posA = g16 ^ (rl & 15);
            half8 ah = *(const half8*)&sU[rl * 128 + posA * 8];
            int gpc = ks * 2 + lhi;
            int posB = (gpc + (n & 3) + ((n >> 2) & 3)) & 3;
            half8 bh = *(const half8*)&Bc[n * 32 + posB * 8];
            half8 bl2 = *(const half8*)&Bc[4096 + n * 32 + posB * 8];
            acc = __builtin_amdgcn_mfma_f32_32x32x16_f16(ah, bh, acc, 0, 0, 0);
            acc = __builtin_amdgcn_mfma_f32_32x32x16_f16(ah, bl2, acc, 0, 0, 0);
        }
    }

    // ---- Pass 1: x @ Wr^T (x 64-k chunks in sU, stride-72) ----
#pragma unroll
    for (int kc64 = 0; kc64 < 2; ++kc64) {
        __syncthreads();  // sU reads of previous phase done
        {
            int row = tid >> 3;  // [0,32)
            int gp8 = tid & 7;
            int nn = n0 + row;
            half8 h = {(_Float16)0.f, (_Float16)0.f, (_Float16)0.f, (_Float16)0.f,
                       (_Float16)0.f, (_Float16)0.f, (_Float16)0.f, (_Float16)0.f};
            if (nn < N) h = Xh[(size_t)nn * 16 + kc64 * 8 + gp8];
            int pos8 = (gp8 + (row & 7) + ((row >> 3) & 7)) & 7;
            *(half8*)&sU[row * 72 + pos8 * 8] = h;
        }
        __syncthreads();
#pragma unroll
        for (int kc4 = 2 * kc64; kc4 < 2 * kc64 + 2; ++kc4) {
            const _Float16* Bc = Bimg + 32768 + (size_t)kc4 * 8192;
#pragma unroll
            for (int ks = 0; ks < 2; ++ks) {
                int gp8 = (kc4 & 1) * 4 + ks * 2 + lhi;
                int posA8 = (gp8 + (rl & 7) + ((rl >> 3) & 7)) & 7;
                half8 ah = *(const half8*)&sU[rl * 72 + posA8 * 8];
                int gpc = ks * 2 + lhi;
                int posB = (gpc + (n & 3) + ((n >> 2) & 3)) & 3;
                half8 bh = *(const half8*)&Bc[n * 32 + posB * 8];
                half8 bl2 = *(const half8*)&Bc[4096 + n * 32 + posB * 8];
                acc = __builtin_amdgcn_mfma_f32_32x32x16_f16(ah, bh, acc, 0, 0, 0);
                acc = __builtin_amdgcn_mfma_f32_32x32x16_f16(ah, bl2, acc, 0, 0, 0);
            }
        }
    }

    // epilogue: relu + fp16 store. C/D 32x32: row=(r&3)+8*(r>>2)+4*lhi, col=l31
#pragma unroll
    for (int r = 0; r < 16; ++r) {
        int row = n0 + (r & 3) + 8 * (r >> 2) + 4 * lhi;
        if (row < N) Yh[(size_t)row * H + n] = (_Float16)fmaxf(acc[r], 0.f);
    }
}

// ---------------- MFMA final linear + cosine (round-0 proven) ------------
// Block 256 = 4 waves; each wave an independent 32-row stripe x 128 cols
// (nt=4). 128 rows/block. LDS: sA 18 KB (stride-72) + sB 16 KB = 34 KB.

__global__ __launch_bounds__(256) void final_mfma6(
    const half8* __restrict__ Xh, const _Float16* __restrict__ Bimg,  // Wlin
    const float* __restrict__ blin, const float* __restrict__ qn,
    const int* __restrict__ bv, float* __restrict__ out, int N) {
    __shared__ __align__(16) _Float16 sA[9216];  // 128 rows x stride 72
    __shared__ __align__(16) _Float16 sB[8192];

    int tid = threadIdx.x;
    int w = tid >> 6;
    int lane = tid & 63;
    int l31 = lane & 31;
    int lhi = lane >> 5;
    int n0 = blockIdx.x * 128;

    int arow = n0 + w * 32 + l31;
    arow = arow < N ? arow : N - 1;
    int gl = bv[arow];  // stripe's graph ids, indexed by l31

    f32x16 acc[4];
#pragma unroll
    for (int nt = 0; nt < 4; ++nt) {
        float b = blin[nt * 32 + l31];
#pragma unroll
        for (int r = 0; r < 16; ++r) acc[nt][r] = b;
    }

    int rl = w * 32 + l31;

    for (int kc4 = 0; kc4 < 4; ++kc4) {
        if (kc4) __syncthreads();
        {
            const half8* bsrc = (const half8*)(Bimg + (size_t)kc4 * 8192);
            half8* bdst = (half8*)sB;
#pragma unroll
            for (int i = 0; i < 4; ++i) bdst[tid + i * 256] = bsrc[tid + i * 256];
        }
        if ((kc4 & 1) == 0) {
            int kc64 = kc4 >> 1;
#pragma unroll
            for (int i = 0; i < 4; ++i) {
                int idx = tid + i * 256;  // [0,1024)
                int row = idx >> 3;       // [0,128)
                int gp8 = idx & 7;
                int nn = n0 + row;
                half8 h = {(_Float16)0.f, (_Float16)0.f, (_Float16)0.f, (_Float16)0.f,
                           (_Float16)0.f, (_Float16)0.f, (_Float16)0.f, (_Float16)0.f};
                if (nn < N) h = Xh[(size_t)nn * 16 + kc64 * 8 + gp8];
                int pos8 = (gp8 + (row & 7) + ((row >> 3) & 7)) & 7;
                *(half8*)&sA[row * 72 + pos8 * 8] = h;
            }
        }
        __syncthreads();
#pragma unroll
        for (int ks = 0; ks < 2; ++ks) {
            int gp8 = (kc4 & 1) * 4 + ks * 2 + lhi;
            int posA8 = (gp8 + (rl & 7) + ((rl >> 3) & 7)) & 7;
            half8 ah = *(const half8*)&sA[rl * 72 + posA8 * 8];
#pragma unroll
            for (int nt = 0; nt < 4; ++nt) {
                int nn = nt * 32 + l31;
                int gpc = ks * 2 + lhi;
                int posB = (gpc + (nn & 3) + ((nn >> 2) & 3)) & 3;
                half8 bh = *(const half8*)&sB[nn * 32 + posB * 8];
                half8 bl2 = *(const half8*)&sB[4096 + nn * 32 + posB * 8];
                acc[nt] = __builtin_amdgcn_mfma_f32_32x32x16_f16(ah, bh, acc[nt], 0, 0, 0);
                acc[nt] = __builtin_amdgcn_mfma_f32_32x32x16_f16(ah, bl2, acc[nt], 0, 0, 0);
            }
        }
    }

    // cosine epilogue: row rloc owned by 32 lanes (l31); xor<=16 stays in group
#pragma unroll
    for (int r = 0; r < 16; ++r) {
        int rloc = (r & 3) + 8 * (r >> 2) + 4 * lhi;
        int row = n0 + w * 32 + rloc;
        int g = __shfl(gl, rloc, 32);  // stripe-row rloc's graph id
        float ss = 0.f, sd = 0.f;
#pragma unroll
        for (int nt = 0; nt < 4; ++nt) {
            float y = acc[nt][r];
            float q = qn[(size_t)g * H + nt * 32 + l31];
            ss = fmaf(y, y, ss);
            sd = fmaf(y, q, sd);
        }
#pragma unroll
        for (int off = 1; off <= 16; off <<= 1) {
            ss += __shfl_xor(ss, off, 64);
            sd += __shfl_xor(sd, off, 64);
        }
        if (l31 == 0 && row < N) out[row] = sd / fmaxf(sqrtf(ss), 1e-12f);
    }
}

// ---------------- launch ----------------

extern "C" void kernel_launch(void* const* d_in, const int* in_sizes, int n_in,
                              void* d_out, int out_size, void* d_ws, size_t ws_size,
                              hipStream_t stream) {
    const float* x = (const float*)d_in[0];
    const float* query = (const float*)d_in[1];
    const float* Wl = (const float*)d_in[2];
    const float* bl = (const float*)d_in[3];
    const float* Wr = (const float*)d_in[4];
    const float* Wlin = (const float*)d_in[5];
    const float* blin = (const float*)d_in[6];
    const int* ei = (const int*)d_in[7];
    const int* bv = (const int*)d_in[8];
    float* out = (float*)d_out;

    const int N = in_sizes[0] / H;
    const int E = in_sizes[7] / 2;
    const int G = in_sizes[1] / H;

    char* p = (char*)d_ws;
    auto alloc = [&](size_t bytes) {
        char* r = p;
        p += (bytes + 255) & ~(size_t)255;
        return r;
    };
    int* deg = (int*)alloc((size_t)(2 * N + 1) * sizeof(int));  // deg|cursor|gcur
    int* cursor = deg + N;
    int* gcur = deg + 2 * N;
    int* offsets = (int*)alloc((size_t)N * sizeof(int));
    int* adj = (int*)alloc((size_t)E * sizeof(int));
    float* qn = (float*)alloc((size_t)G * H * sizeof(float));
    _Float16* wimg = (_Float16*)alloc((size_t)7 * 32768 * sizeof(_Float16));
    size_t actH = (size_t)N * H * sizeof(_Float16);
    _Float16* xah = (_Float16*)alloc(actH);
    _Float16* xbh = (_Float16*)alloc(actH);

    hipMemsetAsync(deg, 0, (size_t)(2 * N + 1) * sizeof(int), stream);

    const int n8 = N * H / 8;
    const int HB = (E + 255) / 256;
    const int SB = (n8 + 255) / 256;
    const int WB = (7 * 2048 + 255) / 256;
    prep_all<<<HB + SB + WB + G, 256, 0, stream>>>(ei, E, deg, x, query, Wl, Wr,
                                                   Wlin, xah, wimg, qn, n8, HB,
                                                   SB, WB);
    scan_atomic<<<(N + 255) / 256, 256, 0, stream>>>(deg, offsets, gcur, N);
    fill_adj<<<(E + 255) / 256, 256, 0, stream>>>(ei, E, offsets, cursor, adj);

    const int NGm = (N + 31) / 32;    // fused layer blocks (32-row tiles)
    const int NGf = (N + 127) / 128;  // final blocks

    layer_fused<<<NGm, 256, 0, stream>>>(
        (const half8*)xah, deg, offsets, adj, wimg + (size_t)0 * 65536,
        bl + 0 * H, xbh, N);
    layer_fused<<<NGm, 256, 0, stream>>>(
        (const half8*)xbh, deg, offsets, adj, wimg + (size_t)1 * 65536,
        bl + 1 * H, xah, N);
    layer_fused<<<NGm, 256, 0, stream>>>(
        (const half8*)xah, deg, offsets, adj, wimg + (size_t)2 * 65536,
        bl + 2 * H, xbh, N);
    final_mfma6<<<NGf, 256, 0, stream>>>(
        (const half8*)xbh, wimg + (size_t)6 * 32768, blin, qn, bv, out, N);
}

// Round 3
// 268.641 us; speedup vs baseline: 1.0565x; 1.0152x over previous
//
#include <hip/hip_runtime.h>
#include <math.h>

#define H 128

typedef _Float16 half8 __attribute__((ext_vector_type(8)));
typedef float f32x16 __attribute__((ext_vector_type(16)));
typedef int int4v __attribute__((ext_vector_type(4)));

__device__ __forceinline__ half8 h8max(half8 a, half8 b) {
#if defined(__has_builtin) && __has_builtin(__builtin_elementwise_max)
    return __builtin_elementwise_max(a, b);
#else
    half8 r;
#pragma unroll
    for (int j = 0; j < 8; ++j) r[j] = a[j] > b[j] ? a[j] : b[j];
    return r;
#endif
}

__device__ __forceinline__ half8 h8shfl_xor(half8 v, int mask) {
    int4v iv;
    __builtin_memcpy(&iv, &v, 16);
#pragma unroll
    for (int j = 0; j < 4; ++j) iv[j] = __shfl_xor(iv[j], mask, 64);
    half8 r;
    __builtin_memcpy(&r, &iv, 16);
    return r;
}

// ---------------- CSR build ----------------

__global__ __launch_bounds__(256) void scan_atomic(const int* __restrict__ deg,
                                                   int* __restrict__ offsets,
                                                   int* __restrict__ gcur, int N) {
    __shared__ int buf[256];
    __shared__ int sbase;
    int tid = threadIdx.x;
    int i = blockIdx.x * 256 + tid;
    int v = (i < N) ? deg[i] : 0;
    int incl = v;
    buf[tid] = v;
    __syncthreads();
#pragma unroll
    for (int off = 1; off < 256; off <<= 1) {
        int t = (tid >= off) ? buf[tid - off] : 0;
        __syncthreads();
        incl += t;
        buf[tid] = incl;
        __syncthreads();
    }
    if (tid == 255) sbase = atomicAdd(gcur, incl);
    __syncthreads();
    if (i < N) offsets[i] = sbase + incl - v;
}

__global__ __launch_bounds__(256) void fill_adj(const int* __restrict__ ei, int E,
                                                const int* __restrict__ offsets,
                                                int* __restrict__ cursor,
                                                int* __restrict__ adj) {
    int e = blockIdx.x * 256 + threadIdx.x;
    if (e < E) {
        int s = ei[e];
        int d = ei[E + e];
        int pos = atomicAdd(&cursor[d], 1);
        adj[offsets[d] + pos] = s;
    }
}

// ---------------- merged prep ----------------
// Weight images:
//   mats 0-5 (Wl0,Wr0,Wl1,Wr1,Wl2,Wr2): WAVE-LINEAR layout. Per mat 32768
//   halves: [kc4:4][s = ks*4+colgrp :8][lane:64][hi8|lo8]. A wave-iteration
//   (kc4,ks,colgrp=w) reads a dense 2 KB: Bimg[kc4*8192 + s*1024 + lane*16].
//   Fragment (lhi=lane>>5,l31=lane&31): n=colgrp*32+l31, g16=kc4*4+ks*2+lhi,
//   hi/lo of W[n][g16*8..+7].
//   mat 6 (Wlin): legacy chunk layout for final_mfma6.

__global__ __launch_bounds__(256) void prep_all(
    const int* __restrict__ ei, int E, int* __restrict__ deg,
    const float* __restrict__ x, const float* __restrict__ query,
    const float* __restrict__ Wl, const float* __restrict__ Wr,
    const float* __restrict__ Wlin, _Float16* __restrict__ xh,
    _Float16* __restrict__ wimg, float* __restrict__ qn, int n8, int HB, int SB,
    int WB) {
    int b = blockIdx.x;
    int tid = threadIdx.x;
    if (b < HB) {
        int e = b * 256 + tid;
        if (e < E) atomicAdd(&deg[ei[E + e]], 1);
    } else if (b < HB + SB) {
        int i = (b - HB) * 256 + tid;
        if (i < n8) {
            const float4* x4 = (const float4*)x;
            float4 u = x4[(size_t)i * 2], v = x4[(size_t)i * 2 + 1];
            float f[8] = {u.x, u.y, u.z, u.w, v.x, v.y, v.z, v.w};
            half8 h;
#pragma unroll
            for (int j = 0; j < 8; ++j) h[j] = (_Float16)f[j];
            *(half8*)(xh + (size_t)i * 8) = h;
        }
    } else if (b < HB + SB + WB) {
        int gidx = (b - HB - SB) * 256 + tid;
        if (gidx < 7 * 2048) {
            int mat = gidx / 2048;
            int rem = gidx - mat * 2048;
            if (mat == 6) {
                // legacy layout for Wlin
                int n = rem >> 4;
                int g = rem & 15;
                const float* p = Wlin + n * H + g * 8;
                half8 h, l;
#pragma unroll
                for (int j = 0; j < 8; ++j) {
                    float v = p[j];
                    _Float16 hh = (_Float16)v;
                    h[j] = hh;
                    l[j] = (_Float16)(v - (float)hh);
                }
                int kc4 = g >> 2, gpc = g & 3;
                int posB = (gpc + (n & 3) + ((n >> 2) & 3)) & 3;
                size_t base =
                    (size_t)mat * 32768 + (size_t)kc4 * 8192 + n * 32 + posB * 8;
                *(half8*)(wimg + base) = h;
                *(half8*)(wimg + base + 4096) = l;
            } else {
                // wave-linear layout for layer weights
                int kc4 = rem >> 9;       // [0,4)
                int r2 = rem & 511;
                int s = r2 >> 6;          // [0,8) = ks*4 + colgrp
                int lane = r2 & 63;
                int ks = s >> 2;
                int colgrp = s & 3;
                int lhi = lane >> 5, l31 = lane & 31;
                int n = colgrp * 32 + l31;
                int g16 = kc4 * 4 + ks * 2 + lhi;
                const float* src = (mat & 1) ? Wr + (mat >> 1) * H * H
                                             : Wl + (mat >> 1) * H * H;
                const float* p = src + n * H + g16 * 8;
                half8 h, l;
#pragma unroll
                for (int j = 0; j < 8; ++j) {
                    float v = p[j];
                    _Float16 hh = (_Float16)v;
                    h[j] = hh;
                    l[j] = (_Float16)(v - (float)hh);
                }
                size_t base = (size_t)mat * 32768 + (size_t)kc4 * 8192 +
                              (size_t)s * 1024 + (size_t)lane * 16;
                *(half8*)(wimg + base) = h;
                *(half8*)(wimg + base + 8) = l;
            }
        }
    } else {
        int g = b - HB - SB - WB;
        __shared__ float part[4];
        float v = (tid < 128) ? query[g * H + tid] : 0.f;
        float ss = v * v;
#pragma unroll
        for (int off = 32; off > 0; off >>= 1) ss += __shfl_xor(ss, off, 64);
        if ((tid & 63) == 0) part[tid >> 6] = ss;
        __syncthreads();
        float tot = part[0] + part[1];
        if (tid < 128) qn[g * H + tid] = v / fmaxf(sqrtf(tot), 1e-12f);
    }
}

// ---------------- fused layer v4: 32-row tile, dense-global B, 2 barriers --
// Y = relu(segmax(X) @ Wl^T + bias + X @ Wr^T).
// Tile 32 rows x 128 cols, 4 waves each owning a 32-col quarter (M=32 MFMA).
// B read directly from the wave-linear L2-resident image: dense 2 KB per
// wave-iteration, zero overfetch, no LDS staging, no barriers.
// A: sU = gather image (XOR-16), sX = block's own x rows (XOR-16), staged
// once right after the gather barrier (loads hide under pass 0).
// Only 2 __syncthreads total.
// Gather: wave-per-8-nodes, adjacency preloaded to 4 regs/lane, consumed via
// shfl; two-level degree body (16 slots + 16 if d>16, wave-uniform branch).

__global__ __launch_bounds__(256, 8) void layer_fused(
    const half8* __restrict__ Xh, const int* __restrict__ deg,
    const int* __restrict__ offsets, const int* __restrict__ adj,
    const _Float16* __restrict__ Bimg, const float* __restrict__ bias,
    _Float16* __restrict__ Yh, int N) {
    __shared__ __align__(16) _Float16 sU[4096];  // m image (32x128, XOR-16)
    __shared__ __align__(16) _Float16 sX[4096];  // x image (32x128, XOR-16)

    int tid = threadIdx.x;
    int w = tid >> 6;
    int lane = tid & 63;
    int l31 = lane & 31;
    int lhi = lane >> 5;
    int n0 = blockIdx.x * 32;

    // ---- Phase G: gather segment-max (8 nodes per wave) ----
    {
        int sub = lane >> 4;
        int lf = lane & 15;
        const _Float16 ni = (_Float16)(-INFINITY);
        const half8 ninf = {ni, ni, ni, ni, ni, ni, ni, ni};
        const half8 hz = {(_Float16)0.f, (_Float16)0.f, (_Float16)0.f, (_Float16)0.f,
                          (_Float16)0.f, (_Float16)0.f, (_Float16)0.f, (_Float16)0.f};
        int nd = n0 + w * 8 + (lf & 7);
        int ndc = nd < N ? nd : N - 1;
        int e0v = offsets[ndc];
        int degv = (nd < N) ? deg[ndc] : 0;

        int dmx = degv;
#pragma unroll
        for (int off = 1; off <= 8; off <<= 1) {
            int t = __shfl_xor(dmx, off, 64);
            dmx = t > dmx ? t : dmx;
        }

        if (dmx <= 32) {
            // adjacency preload: reg rr holds nodes (2rr, 2rr+1); lane l
            // holds slot l&31 of node 2rr + (l>>5), clamped to last entry.
            int adjf[4];
#pragma unroll
            for (int rr = 0; rr < 4; ++rr) {
                int i = 2 * rr + (lane >> 5);
                int e0 = __shfl(e0v, i, 64);
                int d = __shfl(degv, i, 64);
                int s = lane & 31;
                int p = d > 0 ? e0 + (s < d ? s : d - 1) : 0;
                adjf[rr] = adj[p];
            }
#pragma unroll
            for (int i = 0; i < 8; ++i) {
                int d = __shfl(degv, i, 64);
                int dm1 = d > 0 ? d - 1 : 0;
                int srcb = (i & 1) << 5;
                // slots 0..15 (covers d<=16, ~85% of nodes)
                int j0 = sub, j1 = 4 + sub, j2 = 8 + sub, j3 = 12 + sub;
                int i0 = __shfl(adjf[i >> 1], srcb | (j0 < d ? j0 : dm1), 64);
                int i1 = __shfl(adjf[i >> 1], srcb | (j1 < d ? j1 : dm1), 64);
                int i2 = __shfl(adjf[i >> 1], srcb | (j2 < d ? j2 : dm1), 64);
                int i3 = __shfl(adjf[i >> 1], srcb | (j3 < d ? j3 : dm1), 64);
                half8 v0 = Xh[(size_t)i0 * 16 + lf];
                half8 v1 = Xh[(size_t)i1 * 16 + lf];
                half8 v2 = Xh[(size_t)i2 * 16 + lf];
                half8 v3 = Xh[(size_t)i3 * 16 + lf];
                half8 acc = h8max(h8max(v0, v1), h8max(v2, v3));
                if (d > 16) {  // wave-uniform
                    int j4 = 16 + sub, j5 = 20 + sub, j6 = 24 + sub, j7 = 28 + sub;
                    int i4 = __shfl(adjf[i >> 1], srcb | (j4 < d ? j4 : dm1), 64);
                    int i5 = __shfl(adjf[i >> 1], srcb | (j5 < d ? j5 : dm1), 64);
                    int i6 = __shfl(adjf[i >> 1], srcb | (j6 < d ? j6 : dm1), 64);
                    int i7 = __shfl(adjf[i >> 1], srcb | (j7 < d ? j7 : dm1), 64);
                    half8 u0 = Xh[(size_t)i4 * 16 + lf];
                    half8 u1 = Xh[(size_t)i5 * 16 + lf];
                    half8 u2 = Xh[(size_t)i6 * 16 + lf];
                    half8 u3 = Xh[(size_t)i7 * 16 + lf];
                    acc = h8max(acc, h8max(h8max(u0, u1), h8max(u2, u3)));
                }
                acc = h8max(acc, h8shfl_xor(acc, 16));
                acc = h8max(acc, h8shfl_xor(acc, 32));
                if (d == 0) acc = hz;
                int row = w * 8 + i;
                if (sub == 0) *(half8*)&sU[row * 128 + ((lf ^ (row & 15)) << 3)] = acc;
            }
        } else {
            // general path (rare): wave-per-node loop
            for (int i = 0; i < 8; ++i) {
                int e0 = __shfl(e0v, i, 64);
                int d = __shfl(degv, i, 64);
                int row = w * 8 + i;
                half8 acc = ninf;
                for (int base = 0; base < d; base += 16) {
                    half8 v[4];
#pragma unroll
                    for (int q = 0; q < 4; ++q) {
                        int j = base + q * 4 + sub;
                        int idx = adj[e0 + (j < d ? j : d - 1)];
                        v[q] = Xh[(size_t)idx * 16 + lf];
                    }
                    acc = h8max(acc, h8max(h8max(v[0], v[1]), h8max(v[2], v[3])));
                }
                acc = h8max(acc, h8shfl_xor(acc, 16));
                acc = h8max(acc, h8shfl_xor(acc, 32));
                if (d == 0) acc = hz;
                if (sub == 0) *(half8*)&sU[row * 128 + ((lf ^ (row & 15)) << 3)] = acc;
            }
        }
    }
    __syncthreads();

    // ---- stage sX (block's own rows, full K); loads hide under pass 0 ----
    {
        const half8 hz = {(_Float16)0.f, (_Float16)0.f, (_Float16)0.f, (_Float16)0.f,
                          (_Float16)0.f, (_Float16)0.f, (_Float16)0.f, (_Float16)0.f};
#pragma unroll
        for (int t = 0; t < 2; ++t) {
            int idx = tid + t * 256;  // [0,512)
            int row = idx >> 4;       // [0,32)
            int g = idx & 15;
            int nn = n0 + row;
            half8 h = hz;
            if (nn < N) h = Xh[(size_t)nn * 16 + g];
            *(half8*)&sX[row * 128 + ((g ^ (row & 15)) << 3)] = h;
        }
    }

    f32x16 acc;
    {
        float bvv = bias[w * 32 + l31];
#pragma unroll
        for (int r = 0; r < 16; ++r) acc[r] = bvv;
    }

    int rl = l31;  // this lane's A row within the tile

    // ---- Pass 0: m @ Wl^T (A from sU, B dense-global; no barriers) ----
#pragma unroll
    for (int kc4 = 0; kc4 < 4; ++kc4) {
#pragma unroll
        for (int ks = 0; ks < 2; ++ks) {
            int g16 = kc4 * 4 + ks * 2 + lhi;
            int posA = g16 ^ (rl & 15);
            half8 ah = *(const half8*)&sU[rl * 128 + posA * 8];
            size_t boff =
                (size_t)kc4 * 8192 + (size_t)(ks * 4 + w) * 1024 + (size_t)lane * 16;
            half8 bh = *(const half8*)&Bimg[boff];
            half8 bl2 = *(const half8*)&Bimg[boff + 8];
            acc = __builtin_amdgcn_mfma_f32_32x32x16_f16(ah, bh, acc, 0, 0, 0);
            acc = __builtin_amdgcn_mfma_f32_32x32x16_f16(ah, bl2, acc, 0, 0, 0);
        }
    }

    __syncthreads();  // sX visible

    // ---- Pass 1: x @ Wr^T (A from sX, B dense-global) ----
    const _Float16* Br = Bimg + 32768;
#pragma unroll
    for (int kc4 = 0; kc4 < 4; ++kc4) {
#pragma unroll
        for (int ks = 0; ks < 2; ++ks) {
            int g16 = kc4 * 4 + ks * 2 + lhi;
            int posA = g16 ^ (rl & 15);
            half8 ah = *(const half8*)&sX[rl * 128 + posA * 8];
            size_t boff =
                (size_t)kc4 * 8192 + (size_t)(ks * 4 + w) * 1024 + (size_t)lane * 16;
            half8 bh = *(const half8*)&Br[boff];
            half8 bl2 = *(const half8*)&Br[boff + 8];
            acc = __builtin_amdgcn_mfma_f32_32x32x16_f16(ah, bh, acc, 0, 0, 0);
            acc = __builtin_amdgcn_mfma_f32_32x32x16_f16(ah, bl2, acc, 0, 0, 0);
        }
    }

    // epilogue: relu + fp16 store. C/D 32x32: row=(r&3)+8*(r>>2)+4*lhi, col=l31
    int n = w * 32 + l31;
#pragma unroll
    for (int r = 0; r < 16; ++r) {
        int row = n0 + (r & 3) + 8 * (r >> 2) + 4 * lhi;
        if (row < N) Yh[(size_t)row * H + n] = (_Float16)fmaxf(acc[r], 0.f);
    }
}

// ---------------- MFMA final linear + cosine ----------------
// Block 256 = 4 waves; each wave an independent 32-row stripe x 128 cols
// (nt=4). 128 rows/block. Legacy-layout Wlin image.

__global__ __launch_bounds__(256) void final_mfma6(
    const half8* __restrict__ Xh, const _Float16* __restrict__ Bimg,  // Wlin
    const float* __restrict__ blin, const float* __restrict__ qn,
    const int* __restrict__ bv, float* __restrict__ out, int N) {
    __shared__ __align__(16) _Float16 sA[9216];  // 128 rows x stride 72
    __shared__ __align__(16) _Float16 sB[8192];

    int tid = threadIdx.x;
    int w = tid >> 6;
    int lane = tid & 63;
    int l31 = lane & 31;
    int lhi = lane >> 5;
    int n0 = blockIdx.x * 128;

    int arow = n0 + w * 32 + l31;
    arow = arow < N ? arow : N - 1;
    int gl = bv[arow];  // stripe's graph ids, indexed by l31

    f32x16 acc[4];
#pragma unroll
    for (int nt = 0; nt < 4; ++nt) {
        float b = blin[nt * 32 + l31];
#pragma unroll
        for (int r = 0; r < 16; ++r) acc[nt][r] = b;
    }

    int rl = w * 32 + l31;

    for (int kc4 = 0; kc4 < 4; ++kc4) {
        if (kc4) __syncthreads();
        {
            const half8* bsrc = (const half8*)(Bimg + (size_t)kc4 * 8192);
            half8* bdst = (half8*)sB;
#pragma unroll
            for (int i = 0; i < 4; ++i) bdst[tid + i * 256] = bsrc[tid + i * 256];
        }
        if ((kc4 & 1) == 0) {
            int kc64 = kc4 >> 1;
#pragma unroll
            for (int i = 0; i < 4; ++i) {
                int idx = tid + i * 256;  // [0,1024)
                int row = idx >> 3;       // [0,128)
                int gp8 = idx & 7;
                int nn = n0 + row;
                half8 h = {(_Float16)0.f, (_Float16)0.f, (_Float16)0.f, (_Float16)0.f,
                           (_Float16)0.f, (_Float16)0.f, (_Float16)0.f, (_Float16)0.f};
                if (nn < N) h = Xh[(size_t)nn * 16 + kc64 * 8 + gp8];
                int pos8 = (gp8 + (row & 7) + ((row >> 3) & 7)) & 7;
                *(half8*)&sA[row * 72 + pos8 * 8] = h;
            }
        }
        __syncthreads();
#pragma unroll
        for (int ks = 0; ks < 2; ++ks) {
            int gp8 = (kc4 & 1) * 4 + ks * 2 + lhi;
            int posA8 = (gp8 + (rl & 7) + ((rl >> 3) & 7)) & 7;
            half8 ah = *(const half8*)&sA[rl * 72 + posA8 * 8];
#pragma unroll
            for (int nt = 0; nt < 4; ++nt) {
                int nn = nt * 32 + l31;
                int gpc = ks * 2 + lhi;
                int posB = (gpc + (nn & 3) + ((nn >> 2) & 3)) & 3;
                half8 bh = *(const half8*)&sB[nn * 32 + posB * 8];
                half8 bl2 = *(const half8*)&sB[4096 + nn * 32 + posB * 8];
                acc[nt] = __builtin_amdgcn_mfma_f32_32x32x16_f16(ah, bh, acc[nt], 0, 0, 0);
                acc[nt] = __builtin_amdgcn_mfma_f32_32x32x16_f16(ah, bl2, acc[nt], 0, 0, 0);
            }
        }
    }

    // cosine epilogue: row rloc owned by 32 lanes (l31); xor<=16 stays in group
#pragma unroll
    for (int r = 0; r < 16; ++r) {
        int rloc = (r & 3) + 8 * (r >> 2) + 4 * lhi;
        int row = n0 + w * 32 + rloc;
        int g = __shfl(gl, rloc, 32);  // stripe-row rloc's graph id
        float ss = 0.f, sd = 0.f;
#pragma unroll
        for (int nt = 0; nt < 4; ++nt) {
            float y = acc[nt][r];
            float q = qn[(size_t)g * H + nt * 32 + l31];
            ss = fmaf(y, y, ss);
            sd = fmaf(y, q, sd);
        }
#pragma unroll
        for (int off = 1; off <= 16; off <<= 1) {
            ss += __shfl_xor(ss, off, 64);
            sd += __shfl_xor(sd, off, 64);
        }
        if (l31 == 0 && row < N) out[row] = sd / fmaxf(sqrtf(ss), 1e-12f);
    }
}

// ---------------- launch ----------------

extern "C" void kernel_launch(void* const* d_in, const int* in_sizes, int n_in,
                              void* d_out, int out_size, void* d_ws, size_t ws_size,
                              hipStream_t stream) {
    const float* x = (const float*)d_in[0];
    const float* query = (const float*)d_in[1];
    const float* Wl = (const float*)d_in[2];
    const float* bl = (const float*)d_in[3];
    const float* Wr = (const float*)d_in[4];
    const float* Wlin = (const float*)d_in[5];
    const float* blin = (const float*)d_in[6];
    const int* ei = (const int*)d_in[7];
    const int* bv = (const int*)d_in[8];
    float* out = (float*)d_out;

    const int N = in_sizes[0] / H;
    const int E = in_sizes[7] / 2;
    const int G = in_sizes[1] / H;

    char* p = (char*)d_ws;
    auto alloc = [&](size_t bytes) {
        char* r = p;
        p += (bytes + 255) & ~(size_t)255;
        return r;
    };
    int* deg = (int*)alloc((size_t)(2 * N + 1) * sizeof(int));  // deg|cursor|gcur
    int* cursor = deg + N;
    int* gcur = deg + 2 * N;
    int* offsets = (int*)alloc((size_t)N * sizeof(int));
    int* adj = (int*)alloc((size_t)E * sizeof(int));
    float* qn = (float*)alloc((size_t)G * H * sizeof(float));
    _Float16* wimg = (_Float16*)alloc((size_t)7 * 32768 * sizeof(_Float16));
    size_t actH = (size_t)N * H * sizeof(_Float16);
    _Float16* xah = (_Float16*)alloc(actH);
    _Float16* xbh = (_Float16*)alloc(actH);

    hipMemsetAsync(deg, 0, (size_t)(2 * N + 1) * sizeof(int), stream);

    const int n8 = N * H / 8;
    const int HB = (E + 255) / 256;
    const int SB = (n8 + 255) / 256;
    const int WB = (7 * 2048 + 255) / 256;
    prep_all<<<HB + SB + WB + G, 256, 0, stream>>>(ei, E, deg, x, query, Wl, Wr,
                                                   Wlin, xah, wimg, qn, n8, HB,
                                                   SB, WB);
    scan_atomic<<<(N + 255) / 256, 256, 0, stream>>>(deg, offsets, gcur, N);
    fill_adj<<<(E + 255) / 256, 256, 0, stream>>>(ei, E, offsets, cursor, adj);

    const int NGm = (N + 31) / 32;    // fused layer blocks (32-row tiles)
    const int NGf = (N + 127) / 128;  // final blocks

    layer_fused<<<NGm, 256, 0, stream>>>(
        (const half8*)xah, deg, offsets, adj, wimg + (size_t)0 * 65536,
        bl + 0 * H, xbh, N);
    layer_fused<<<NGm, 256, 0, stream>>>(
        (const half8*)xbh, deg, offsets, adj, wimg + (size_t)1 * 65536,
        bl + 1 * H, xah, N);
    layer_fused<<<NGm, 256, 0, stream>>>(
        (const half8*)xah, deg, offsets, adj, wimg + (size_t)2 * 65536,
        bl + 2 * H, xbh, N);
    final_mfma6<<<NGf, 256, 0, stream>>>(
        (const half8*)xbh, wimg + (size_t)6 * 32768, blin, qn, bv, out, N);
}